// Round 2
// baseline (1594.514 us; speedup 1.0000x reference)
//
#include <hip/hip_runtime.h>
#include <hip/hip_bf16.h>
#include <stdint.h>

typedef unsigned short u16;
typedef __attribute__((ext_vector_type(8))) short short8;
typedef __attribute__((ext_vector_type(4))) float floatx4;

#define T_NUM 16384
#define D_DIM 3072
#define O_DIM 3072
#define E_NUM 8
#define R_DIM 32
#define KA    (E_NUM * R_DIM)   // 256 augmented-K columns

__device__ __forceinline__ float bf2f(u16 u) {
    union { unsigned int i; float f; } v;
    v.i = ((unsigned int)u) << 16;
    return v.f;
}
// fp32 -> bf16 round-to-nearest-even
__device__ __forceinline__ u16 f2bf(float f) {
    union { float f; unsigned int u; } v;
    v.f = f;
    unsigned int r = (v.u + 0x7FFFu + ((v.u >> 16) & 1u)) >> 16;
    return (u16)r;
}

struct f8 { float v[8]; };

// load 8 contiguous elements (element index `idx`) as fp32
template<bool BF>
__device__ __forceinline__ f8 loadf8(const void* p, size_t idx) {
    f8 r;
    if constexpr (BF) {
        short8 s = *(const short8*)((const u16*)p + idx);
#pragma unroll
        for (int j = 0; j < 8; ++j) r.v[j] = bf2f((u16)s[j]);
    } else {
        const float* f = (const float*)p + idx;
        floatx4 a = *(const floatx4*)f;
        floatx4 b = *(const floatx4*)(f + 4);
#pragma unroll
        for (int j = 0; j < 4; ++j) { r.v[j] = a[j]; r.v[4 + j] = b[j]; }
    }
    return r;
}

// load 8 contiguous elements as bf16 bits
template<bool BF>
__device__ __forceinline__ short8 load8bf(const void* p, size_t idx) {
    if constexpr (BF) {
        return *(const short8*)((const u16*)p + idx);
    } else {
        const float* f = (const float*)p + idx;
        floatx4 a = *(const floatx4*)f;
        floatx4 b = *(const floatx4*)(f + 4);
        short8 s;
#pragma unroll
        for (int j = 0; j < 4; ++j) { s[j] = (short)f2bf(a[j]); s[4 + j] = (short)f2bf(b[j]); }
        return s;
    }
}

// ---------------------------------------------------------------------------
// Dtype detector: look at even-indexed u16s of x. If the underlying data is
// fp32, those are low mantissa halves -> uniform bits -> ~80% extreme bf16
// exponents. If bf16, they are real N(0,1) bf16 values -> ~0% extreme.
// flag = 1 => bf16 data, 0 => fp32 data.
// ---------------------------------------------------------------------------
__global__ void detect_kernel(const u16* __restrict__ x16, int* __restrict__ flag) {
    __shared__ int cnt;
    if (threadIdx.x == 0) cnt = 0;
    __syncthreads();
    int local = 0;
#pragma unroll
    for (int i = 0; i < 32; ++i) {
        u16 u = x16[(size_t)(threadIdx.x * 32 + i) * 2];
        int e = (u >> 7) & 0xFF;
        local += (e < 100 || e > 150) ? 1 : 0;
    }
    atomicAdd(&cnt, local);
    __syncthreads();
    if (threadIdx.x == 0) *flag = (cnt < 2048) ? 1 : 0;
}

// ---------------------------------------------------------------------------
// Router: one wave per token. logits = x[t]·gate_w[e]; top-2 renormalized
// softmax; writes dense per-expert scales (×2 = LORA_ALPHA/LORA_R folded in).
// ---------------------------------------------------------------------------
template<bool BF>
__global__ __launch_bounds__(256) void routing_kernel(
    const void* __restrict__ x, const void* __restrict__ gate_w,
    float* __restrict__ s_te, const int* __restrict__ flag, int want)
{
    if (*flag != want) return;
    int lane = threadIdx.x & 63;
    int wave = threadIdx.x >> 6;
    int t = blockIdx.x * 4 + wave;

    float acc[E_NUM];
#pragma unroll
    for (int e = 0; e < E_NUM; ++e) acc[e] = 0.f;

#pragma unroll
    for (int i = 0; i < 6; ++i) {               // 6 * 64 lanes * 8 = 3072
        size_t d = (size_t)(i * 64 + lane) * 8;
        f8 xv = loadf8<BF>(x, (size_t)t * D_DIM + d);
#pragma unroll
        for (int e = 0; e < E_NUM; ++e) {
            f8 gv = loadf8<BF>(gate_w, (size_t)e * D_DIM + d);
#pragma unroll
            for (int j = 0; j < 8; ++j) acc[e] += xv.v[j] * gv.v[j];
        }
    }
#pragma unroll
    for (int e = 0; e < E_NUM; ++e) {
#pragma unroll
        for (int off = 32; off > 0; off >>= 1)
            acc[e] += __shfl_xor(acc[e], off, 64);
    }
    if (lane == 0) {
        int i0 = 0; float l0 = acc[0];
        for (int e = 1; e < E_NUM; ++e) if (acc[e] > l0) { l0 = acc[e]; i0 = e; }
        int i1 = -1; float l1 = -1e30f;
        for (int e = 0; e < E_NUM; ++e) if (e != i0 && acc[e] > l1) { l1 = acc[e]; i1 = e; }
        float w0 = 1.f / (1.f + __expf(l1 - l0));   // renormalized top-2 softmax
        float w1 = 1.f - w0;
        float s[E_NUM];
#pragma unroll
        for (int e = 0; e < E_NUM; ++e) s[e] = 0.f;
        s[i0] = 2.f * w0;
        s[i1] = 2.f * w1;
#pragma unroll
        for (int e = 0; e < E_NUM; ++e) s_te[(size_t)t * E_NUM + e] = s[e];
    }
}

// ---------------------------------------------------------------------------
// Pack lora_B [E,O,R] -> B_pack [O, E*R] (bf16, K-major like W).
// ---------------------------------------------------------------------------
template<bool BF>
__global__ __launch_bounds__(256) void pack_b_kernel(
    const void* __restrict__ loraB, u16* __restrict__ Bp,
    const int* __restrict__ flag, int want)
{
    if (*flag != want) return;
    int idx = blockIdx.x * 256 + threadIdx.x;     // idx = e*O + o
    int e = idx / O_DIM;
    int o = idx - e * O_DIM;
#pragma unroll
    for (int i = 0; i < 4; ++i) {
        short8 s = load8bf<BF>(loraB, (size_t)idx * R_DIM + i * 8);
        *(short8*)(Bp + (size_t)o * KA + e * R_DIM + i * 8) = s;
    }
}

// ---------------------------------------------------------------------------
// 128x128 MFMA GEMM, BK=64, 4 waves of 64x64, dual K-source. Source-1 pair
// (A1,B1) has dtype BF1; source-2 pair (A2,B2) is always bf16 workspace.
// Register staging (global vec-load -> ds_write_b128). out = A·B^T.
// ---------------------------------------------------------------------------
template<bool BF1, bool OUTBF>
__global__ __launch_bounds__(256) void gemm_kernel(
    const void* __restrict__ A1, int lda1, int kt1,
    const u16* __restrict__ A2, int lda2, int kt2,
    const void* __restrict__ B1, int ldb1,
    const u16* __restrict__ B2, int ldb2,
    void* __restrict__ outv, int ldo,
    const float* __restrict__ s_te, int scale_mode,
    const int* __restrict__ flag, int want)
{
    if (*flag != want) return;
    __shared__ short As[128 * 64];
    __shared__ short Bs[128 * 64];

    const int tid  = threadIdx.x;
    const int lane = tid & 63;
    const int wave = tid >> 6;
    const int rowA0 = blockIdx.x * 128;
    const int rowB0 = blockIdx.y * 128;

    floatx4 acc[4][4];
#pragma unroll
    for (int mi = 0; mi < 4; ++mi)
#pragma unroll
        for (int ni = 0; ni < 4; ++ni)
            acc[mi][ni] = (floatx4){0.f, 0.f, 0.f, 0.f};

    const int m_base = (wave & 1) * 64;
    const int n_base = (wave >> 1) * 64;
    const int quad = lane >> 4;
    const int r16  = lane & 15;

    const int ktot = kt1 + kt2;
    for (int kt = 0; kt < ktot; ++kt) {
        const bool first = (kt < kt1);
        // stage 128x64 bf16 A and B tiles: 1024 chunks of 8 elems each.
#pragma unroll
        for (int i = 0; i < 4; ++i) {
            int c = wave * 256 + i * 64 + lane;
            int r = c >> 3, c8 = c & 7;
            short8 av, bv;
            if (first) {
                int ko = kt * 64;
                av = load8bf<BF1>(A1, (size_t)(rowA0 + r) * lda1 + ko + c8 * 8);
                bv = load8bf<BF1>(B1, (size_t)(rowB0 + r) * ldb1 + ko + c8 * 8);
            } else {
                int ko = (kt - kt1) * 64;
                av = *(const short8*)(A2 + (size_t)(rowA0 + r) * lda2 + ko + c8 * 8);
                bv = *(const short8*)(B2 + (size_t)(rowB0 + r) * ldb2 + ko + c8 * 8);
            }
            *(short8*)(As + (size_t)c * 8) = av;
            *(short8*)(Bs + (size_t)c * 8) = bv;
        }
        __syncthreads();

#pragma unroll
        for (int kk = 0; kk < 64; kk += 32) {
            short8 af[4], bfg[4];
#pragma unroll
            for (int mi = 0; mi < 4; ++mi)
                af[mi] = *(const short8*)(As + (m_base + mi * 16 + r16) * 64 + kk + quad * 8);
#pragma unroll
            for (int ni = 0; ni < 4; ++ni)
                bfg[ni] = *(const short8*)(Bs + (n_base + ni * 16 + r16) * 64 + kk + quad * 8);
#pragma unroll
            for (int mi = 0; mi < 4; ++mi)
#pragma unroll
                for (int ni = 0; ni < 4; ++ni)
                    acc[mi][ni] = __builtin_amdgcn_mfma_f32_16x16x32_bf16(
                        af[mi], bfg[ni], acc[mi][ni], 0, 0, 0);
        }
        __syncthreads();
    }

    // Epilogue. C/D layout (m89-verified): col n = lane&15, row m = quad*4+reg.
#pragma unroll
    for (int mi = 0; mi < 4; ++mi) {
#pragma unroll
        for (int r = 0; r < 4; ++r) {
            int t = rowA0 + m_base + mi * 16 + quad * 4 + r;
#pragma unroll
            for (int ni = 0; ni < 4; ++ni) {
                int o = rowB0 + n_base + ni * 16 + r16;
                float v = acc[mi][ni][r];
                if (scale_mode) v *= s_te[(size_t)t * E_NUM + (o >> 5)];
                if constexpr (OUTBF)
                    ((u16*)outv)[(size_t)t * ldo + o] = f2bf(v);
                else
                    ((float*)outv)[(size_t)t * ldo + o] = v;
            }
        }
    }
}

// ---------------------------------------------------------------------------
extern "C" void kernel_launch(void* const* d_in, const int* in_sizes, int n_in,
                              void* d_out, int out_size, void* d_ws, size_t ws_size,
                              hipStream_t stream)
{
    const void* x      = d_in[0];   // [T, D]
    const void* W      = d_in[1];   // [O, D]
    const void* gate_w = d_in[2];   // [E, D]
    const void* lora_A = d_in[3];   // [E*R, D]
    const void* lora_B = d_in[4];   // [E, O, R]

    // workspace layout (~10.4 MB)
    int*   flag     = (int*)d_ws;
    float* s_te     = (float*)((char*)d_ws + 1024);
    u16*   a_scaled = (u16*)((char*)d_ws + 1024 + 524288);                 // [T, 256] bf16
    u16*   B_pack   = (u16*)((char*)d_ws + 1024 + 524288 + 8388608);       // [O, 256] bf16

    detect_kernel<<<1, 256, 0, stream>>>((const u16*)x, flag);

    routing_kernel<true ><<<T_NUM / 4, 256, 0, stream>>>(x, gate_w, s_te, flag, 1);
    routing_kernel<false><<<T_NUM / 4, 256, 0, stream>>>(x, gate_w, s_te, flag, 0);

    pack_b_kernel<true ><<<(E_NUM * O_DIM) / 256, 256, 0, stream>>>(lora_B, B_pack, flag, 1);
    pack_b_kernel<false><<<(E_NUM * O_DIM) / 256, 256, 0, stream>>>(lora_B, B_pack, flag, 0);

    // GEMM 1: a_scaled[t, e*32+r] = s_te[t,e] * (x[t]·lora_A[e,r])
    gemm_kernel<true , true><<<dim3(T_NUM / 128, KA / 128), 256, 0, stream>>>(
        x, D_DIM, D_DIM / 64, (const u16*)x, D_DIM, 0,
        lora_A, D_DIM, (const u16*)lora_A, D_DIM,
        a_scaled, KA, s_te, 1, flag, 1);
    gemm_kernel<false, true><<<dim3(T_NUM / 128, KA / 128), 256, 0, stream>>>(
        x, D_DIM, D_DIM / 64, (const u16*)x, D_DIM, 0,
        lora_A, D_DIM, (const u16*)lora_A, D_DIM,
        a_scaled, KA, s_te, 1, flag, 0);

    // GEMM 2: out = [x | a_scaled] @ [W | B_pack]^T, K = 3072 + 256
    gemm_kernel<true , true ><<<dim3(T_NUM / 128, O_DIM / 128), 256, 0, stream>>>(
        x, D_DIM, D_DIM / 64, a_scaled, KA, KA / 64,
        W, D_DIM, B_pack, KA,
        d_out, O_DIM, nullptr, 0, flag, 1);
    gemm_kernel<false, false><<<dim3(T_NUM / 128, O_DIM / 128), 256, 0, stream>>>(
        x, D_DIM, D_DIM / 64, a_scaled, KA, 4,
        W, D_DIM, B_pack, KA,
        d_out, O_DIM, nullptr, 0, flag, 0);
}